// Round 8
// baseline (292.140 us; speedup 1.0000x reference)
//
#include <hip/hip_runtime.h>

namespace {
constexpr int Bn = 16, Hn = 512, Wn = 512;
constexpr int HW  = Hn * Wn;        // 262144
constexpr int CHW = 8 * HW;         // 2097152
constexpr int NCOL = Bn * Wn;       // 8192 dice columns
constexpr int WALK = 2;             // rows walked per wave (block = 2 rowgroups)
constexpr int GX   = Hn / (2 * WALK); // 128
constexpr int NBLK = GX * Bn;       // 2048 blocks
constexpr int SLABN = NBLK * 512;   // 1,048,576 floats per partial table
constexpr int FBLK  = 32;           // fallback finisher blocks
constexpr int FBLK2 = 256;          // slab finisher blocks (8 bscal slots each)

constexpr float L2E  = 1.4426950408889634f;   // log2(e)
constexpr float LN2  = 0.6931471805599453f;
constexpr float CLMP = -144.26950408889634f;  // -100 / ln2 (clamp in log2 units)

__device__ __forceinline__ float frcp(float x) { return __builtin_amdgcn_rcpf(x); }
#if __has_builtin(__builtin_amdgcn_exp2f)
__device__ __forceinline__ float fexp2(float x) { return __builtin_amdgcn_exp2f(x); }
#else
__device__ __forceinline__ float fexp2(float x) { return exp2f(x); }
#endif
#if __has_builtin(__builtin_amdgcn_logf)
__device__ __forceinline__ float flog2(float x) { return __builtin_amdgcn_logf(x); }
#else
__device__ __forceinline__ float flog2(float x) { return log2f(x); }
#endif

// non-temporal (streaming, no-L1-allocate) loads — R6's proven lever
typedef float vf4 __attribute__((ext_vector_type(4)));
typedef int   vi4 __attribute__((ext_vector_type(4)));
__device__ __forceinline__ vf4 ntl4f(const float* p) {
    return __builtin_nontemporal_load((const vf4*)p);
}
__device__ __forceinline__ vi4 ntl4i(const int* p) {
    return __builtin_nontemporal_load((const vi4*)p);
}
__device__ __forceinline__ float ntlf(const float* p) {
    return __builtin_nontemporal_load(p);
}
} // namespace

// n[c](h,w) = sigmoid(c_map[c][h+DY[c]][w+DX[c]]), zero outside image.
// vote[i] = p[i] * n[7-i].  DX = {1,0,-1,1,-1,1,0,-1}, DY = {1,1,1,0,0,-1,-1,-1}.
// BCE sums in log2 units via log-of-product fusion; one x ln2 at bscal write.
//
// R8: request-granularity probe in the streaming regime. R6 (ILP, occ 19%)
// == R7 (TLP, occ 55%) < 77us: latency-hiding style is not the limiter with
// NT loads. Remaining unprobed axis: TA request RATE. R6/R7 issue ~11.5
// requests/px (8B lanes + 6 unpredicated scalars). Here: R0's 4-col/lane
// geometry (16B float4/int4 NT loads) + R4's shuffle-sourced neighbors
// (boundary scalars only on lanes 0/63) -> ~4.25 requests/px (2.7x fewer),
// same demand bytes. LDS cred merge for dice (two rowgroups share columns),
// slab stores, XCD swizzle.
// Tripwires: VGPR>=180 (2 waves/SIMD knee, R4) or WRITE>>12.4MB -> revert R7.

template <bool SLAB>
__global__ __launch_bounds__(256) void bicon_main(
    const float* __restrict__ c_map,
    const int*   __restrict__ target,
    const int*   __restrict__ con_target,
    float* __restrict__ col_i, float* __restrict__ col_j, float* __restrict__ col_x,
    double* __restrict__ bscal)
{
    const int tid  = threadIdx.x;        // 0..255
    const int lane = tid & 63;
    const int wv   = tid >> 6;           // 0..3
    const int half = wv & 1;             // 256-col half
    const int rg   = wv >> 1;            // row-group within block

    // Bijective XCD-chunk swizzle: each XCD owns 256 consecutive work ids.
    const int hwid = blockIdx.y * GX + blockIdx.x;
    const int work = (hwid & 7) * (NBLK / 8) + (hwid >> 3);
    const int gx   = work & (GX - 1);
    const int b    = work >> 7;          // work / GX

    const int hstart = gx * (2 * WALK) + rg * WALK;
    const int wq   = half * 256 + lane * 4;   // first of this lane's 4 columns

    const float* cm = c_map      + (size_t)b * CHW;
    const int*   ct = con_target + (size_t)b * CHW;
    const int*   tg = target     + (size_t)b * HW;

    float s_con = 0.f, s_bi = 0.f, s_bce = 0.f, s_dec = 0.f;   // log2 units
    float ci[4] = {0, 0, 0, 0}, cj[4] = {0, 0, 0, 0}, cx[4] = {0, 0, 0, 0};

    auto sig4 = [&](const vf4& v, float s[4]) {
        s[0] = frcp(1.f + fexp2(-v.x * L2E));
        s[1] = frcp(1.f + fexp2(-v.y * L2E));
        s[2] = frcp(1.f + fexp2(-v.z * L2E));
        s[3] = frcp(1.f + fexp2(-v.w * L2E));
    };

    const bool lnR = (lane == 63);   // right boundary lane of each wave
    const bool lnL = (lane == 0);    // left boundary lane
    const bool edR = (wq + 4 == Wn); // image right edge (half1 lane63)
    const bool edL = (wq == 0);      // image left edge (half0 lane0)

    // ---- carried window: sigma(ch0..2)@h, sigma(ch5..7)@h-1 ----
    float C0[4], C1[4], C2[4], P5[4], P6[4], P7[4];
    {
        const int pb = hstart * Wn + wq;
        sig4(ntl4f(cm + 0 * HW + pb), C0);
        sig4(ntl4f(cm + 1 * HW + pb), C1);
        sig4(ntl4f(cm + 2 * HW + pb), C2);
    }
    if (hstart > 0) {   // wave-uniform
        const int pb = (hstart - 1) * Wn + wq;
        sig4(ntl4f(cm + 5 * HW + pb), P5);
        sig4(ntl4f(cm + 6 * HW + pb), P6);
        sig4(ntl4f(cm + 7 * HW + pb), P7);
    } else {
#pragma unroll
        for (int k = 0; k < 4; ++k) { P5[k] = 0.f; P6[k] = 0.f; P7[k] = 0.f; }
    }

    int h = hstart;
#pragma unroll 1
    for (int r = 0; r < WALK; ++r, ++h) {
        const int  base  = h * Wn + wq;
        const bool hasDn = (h + 1 < Hn);
        const bool hasUp = (h > 0);

        // ---- vector loads (16B/lane) ----
        const vf4 xa3 = ntl4f(cm + 3 * HW + base);
        const vf4 xa4 = ntl4f(cm + 4 * HW + base);
        const vf4 xa5 = ntl4f(cm + 5 * HW + base);
        const vf4 xa6 = ntl4f(cm + 6 * HW + base);
        const vf4 xa7 = ntl4f(cm + 7 * HW + base);
        const vf4 xf0 = ntl4f(cm + 0 * HW + base + Wn);
        const vf4 xf1 = ntl4f(cm + 1 * HW + base + Wn);
        const vf4 xf2 = ntl4f(cm + 2 * HW + base + Wn);
        const vi4 t4  = ntl4i(tg + base);
        // boundary scalars: only the lane that uses them issues the load
        const float bx0 = lnR ? ntlf(cm + 0 * HW + base + Wn + 4) : 0.f;
        const float bx3 = lnR ? ntlf(cm + 3 * HW + base + 4)      : 0.f;
        const float bx5 = lnR ? ntlf(cm + 5 * HW + base - Wn + 4) : 0.f;
        const float bx2 = lnL ? ntlf(cm + 2 * HW + base + Wn - 1) : 0.f;
        const float bx4 = lnL ? ntlf(cm + 4 * HW + base - 1)      : 0.f;
        const float bx7 = lnL ? ntlf(cm + 7 * HW + base - Wn - 1) : 0.f;

        unsigned lo = 0u;
#pragma unroll
        for (int c = 0; c < 8; ++c) {
            const vi4 u = ntl4i(ct + c * HW + base);
            lo |= ((unsigned)u.x << c)        | ((unsigned)u.y << (8 + c)) |
                  ((unsigned)u.z << (16 + c)) | ((unsigned)u.w << (24 + c));
        }

        // ---- fresh centers ch3-7: sigma + conmap d-product accumulation ----
        float dp[4] = {1.f, 1.f, 1.f, 1.f};   // prod of d over ch3..7
        float ys[4] = {0.f, 0.f, 0.f, 0.f};   // sum of y where bit==0
        float c3[4], c4[4], c5[4], c6[4], c7[4];
        auto fresh = [&](int c, const vf4& v, float s[4]) {
            const float xs[4] = {v.x, v.y, v.z, v.w};
#pragma unroll
            for (int k = 0; k < 4; ++k) {
                const float y = xs[k] * L2E;
                const float e = fexp2(-y);
                const float d = 1.f + e;
                s[k] = frcp(d);
                dp[k] *= d;
                ys[k] += ((lo >> (8 * k + c)) & 1u) ? 0.f : y;
            }
        };
        fresh(3, xa3, c3); fresh(4, xa4, c4); fresh(5, xa5, c5);
        fresh(6, xa6, c6); fresh(7, xa7, c7);

        // ---- conmap: carried ch0-2 select-product + ch3-7 d-form ----
#pragma unroll
        for (int k = 0; k < 4; ++k) {
            const float q0 = ((lo >> (8 * k + 0)) & 1u) ? C0[k] : 1.f - C0[k];
            const float q1 = ((lo >> (8 * k + 1)) & 1u) ? C1[k] : 1.f - C1[k];
            const float q2 = ((lo >> (8 * k + 2)) & 1u) ? C2[k] : 1.f - C2[k];
            s_con += flog2(q0 * q1 * q2) - flog2(dp[k]) - ys[k];
        }

        // ---- next-row sigmas ----
        float F0[4], F1[4], F2[4];
        sig4(xf0, F0); sig4(xf1, F1); sig4(xf2, F2);

        // ---- neighbor values across lanes: shuffle already-computed sigmoids;
        //      lanes 0/63 fall back to scalar-load sigmoids (R4-proven) ----
        const float r0 = __shfl_down(F0[0], 1);
        const float r3 = __shfl_down(c3[0], 1);
        const float r5 = __shfl_down(P5[0], 1);
        const float l2 = __shfl_up(F2[3], 1);
        const float l4 = __shfl_up(c4[3], 1);
        const float l7 = __shfl_up(P7[3], 1);
        const float s0b = frcp(1.f + fexp2(-bx0 * L2E));
        const float s2b = frcp(1.f + fexp2(-bx2 * L2E));
        const float s3b = frcp(1.f + fexp2(-bx3 * L2E));
        const float s4b = frcp(1.f + fexp2(-bx4 * L2E));
        const float s5b = frcp(1.f + fexp2(-bx5 * L2E));
        const float s7b = frcp(1.f + fexp2(-bx7 * L2E));

        // ---- neighbor arrays n[c] (masked shifts) ----
        float n0[4], n1[4], n2[4], n3[4], n4[4], n5[4], n6[4], n7[4];
#pragma unroll
        for (int k = 0; k < 3; ++k) {
            n0[k] = F0[k + 1]; n3[k] = c3[k + 1]; n5[k] = P5[k + 1];
            n2[k + 1] = F2[k]; n4[k + 1] = c4[k]; n7[k + 1] = P7[k];
        }
        n0[3] = edR ? 0.f : (lnR ? s0b : r0);
        n3[3] = edR ? 0.f : (lnR ? s3b : r3);
        n5[3] = edR ? 0.f : (lnR ? s5b : r5);
        n2[0] = edL ? 0.f : (lnL ? s2b : l2);
        n4[0] = edL ? 0.f : (lnL ? s4b : l4);
        n7[0] = edL ? 0.f : (lnL ? s7b : l7);
#pragma unroll
        for (int k = 0; k < 4; ++k) {
            n1[k] = hasDn ? F1[k] : 0.f;
            n6[k] = hasUp ? P6[k] : 0.f;
            if (!hasDn) { n0[k] = 0.f; n2[k] = 0.f; }
            if (!hasUp) { n5[k] = 0.f; n7[k] = 0.f; }
        }

        // ---- votes + bimap product accumulation ----
        float vmax[4] = {0.f, 0.f, 0.f, 0.f}, vmin[4] = {2.f, 2.f, 2.f, 2.f};
        float pr[4]   = {1.f, 1.f, 1.f, 1.f};
        float zc[4]   = {0.f, 0.f, 0.f, 0.f};   // count of bit=1 zero-votes
        auto vote = [&](int i, const float p[4], const float n[4]) {
#pragma unroll
            for (int k = 0; k < 4; ++k) {
                const float v = p[k] * n[k];
                vmax[k] = fmaxf(vmax[k], v);
                vmin[k] = fminf(vmin[k], v);
                const bool bit = (lo >> (8 * k + i)) & 1u;
                const bool z   = bit && (v == 0.f);     // only from masked edges
                float sel = bit ? v : 1.f - v;
                sel = z ? 1.f : sel;
                zc[k] += z ? 1.f : 0.f;
                pr[k] *= sel;
            }
        };
        vote(0, C0, n7); vote(1, C1, n6); vote(2, C2, n5); vote(3, c3, n4);
#pragma unroll
        for (int k = 0; k < 4; ++k) { s_bi += flog2(pr[k]); pr[k] = 1.f; }
        vote(4, c4, n3); vote(5, c5, n2); vote(6, c6, n1); vote(7, c7, n0);
#pragma unroll
        for (int k = 0; k < 4; ++k) { s_bi += flog2(pr[k]) + CLMP * zc[k]; }

        // ---- per-pixel tail ----
        const int tk[4] = {t4.x, t4.y, t4.z, t4.w};
#pragma unroll
        for (int k = 0; k < 4; ++k) {
            const float fm = vmax[k];
            s_bce += fmaxf(flog2(tk[k] ? fm : 1.f - fm), CLMP);
            const int sc = __popc((int)((lo >> (8 * k)) & 0xffu));
            s_dec += (sc > 0 && sc < 8) ? fmaxf(flog2(1.f - vmin[k]), CLMP) : 0.f;
            ci[k] += (float)tk[k];
            cj[k] += fm;
            cx[k] += tk[k] ? fm : 0.f;
        }

        // ---- rotate window ----
#pragma unroll
        for (int k = 0; k < 4; ++k) {
            C0[k] = F0[k]; C1[k] = F1[k]; C2[k] = F2[k];
            P5[k] = c5[k]; P6[k] = c6[k]; P7[k] = c7[k];
        }
    }

    // ---- dice partials -> LDS (two rowgroups share each column) ----
    __shared__ float cred[3][4][256];   // 12 KB
#pragma unroll
    for (int k = 0; k < 4; ++k) {
        cred[0][wv][(lane << 2) + k] = ci[k];
        cred[1][wv][(lane << 2) + k] = cj[k];
        cred[2][wv][(lane << 2) + k] = cx[k];
    }

    // ---- scalar sums: wave shuffle reduction ----
#pragma unroll
    for (int off = 32; off > 0; off >>= 1) {
        s_con += __shfl_down(s_con, off);
        s_bi  += __shfl_down(s_bi,  off);
        s_bce += __shfl_down(s_bce, off);
        s_dec += __shfl_down(s_dec, off);
    }
    __shared__ float wred[4][4];
    if (lane == 0) {   // convert log2 -> ln units here (one mul per sum)
        wred[wv][0] = s_con * LN2; wred[wv][1] = s_bi * LN2;
        wred[wv][2] = s_bce * LN2; wred[wv][3] = s_dec * LN2;
    }
    __syncthreads();

    if constexpr (SLAB) {
        // direct per-block partial store: zero contention, coalesced dwords
        const size_t sb = ((size_t)work) << 9;
#pragma unroll
        for (int j = tid; j < 512; j += 256) {
            const int hj = j >> 8, cidx = j & 255;   // waves {hj, hj+2} = half hj
            col_i[sb + j] = cred[0][hj][cidx] + cred[0][hj + 2][cidx];
            col_j[sb + j] = cred[1][hj][cidx] + cred[1][hj + 2][cidx];
            col_x[sb + j] = cred[2][hj][cidx] + cred[2][hj + 2][cidx];
        }
    } else {
#pragma unroll
        for (int j = tid; j < 512; j += 256) {
            const int hj = j >> 8, cidx = j & 255;
            atomicAdd(&col_i[b * Wn + j], cred[0][hj][cidx] + cred[0][hj + 2][cidx]);
            atomicAdd(&col_j[b * Wn + j], cred[1][hj][cidx] + cred[1][hj + 2][cidx]);
            atomicAdd(&col_x[b * Wn + j], cred[2][hj][cidx] + cred[2][hj + 2][cidx]);
        }
    }
    if (tid < 4) {
        bscal[(size_t)work * 4 + tid] =
            (double)(wred[0][tid] + wred[1][tid] + wred[2][tid] + wred[3][tid]);
    }
}

// Slab finisher: 256 blocks x 256 threads. Block bx owns 32 columns; each
// column's 128 gx-partials are summed by 8 threads (16 each) -> LDS -> lane.
__global__ __launch_bounds__(256) void bicon_finish_slab(
    const float* __restrict__ pI,
    const float* __restrict__ pJ,
    const float* __restrict__ pX,
    const double* __restrict__ bscal,
    float* __restrict__ out)
{
    const int tid = threadIdx.x;
    const int w32 = tid & 31;                 // which of the block's 32 columns
    const int p   = tid >> 5;                 // gx partition 0..7 (16 gx each)
    const int col = blockIdx.x * 32 + w32;    // 0..8191
    const int b   = col >> 9;
    const int w   = col & 511;

    float fi = 0.f, fj = 0.f, fx = 0.f;
    const size_t base = (((size_t)(b * GX + p * 16)) << 9) + w;
#pragma unroll
    for (int g = 0; g < 16; ++g) {
        const size_t idx = base + ((size_t)g << 9);
        fi += pI[idx]; fj += pJ[idx]; fx += pX[idx];
    }
    __shared__ float red[3][8][32];           // 3 KB
    red[0][p][w32] = fi; red[1][p][w32] = fj; red[2][p][w32] = fx;
    __syncthreads();

    double part = 0.0;
    if (tid < 32) {                           // dice term for 32 columns
        float si = 0.f, sj = 0.f, sx = 0.f;
#pragma unroll
        for (int q = 0; q < 8; ++q) {
            si += red[0][q][tid]; sj += red[1][q][tid]; sx += red[2][q][tid];
        }
        part = (1.0 - (2.0 * (double)sx + 0.001) /
                      ((double)si + (double)sj + 0.001)) / 8192.0;
    }
    if (tid >= 64 && tid < 72) {              // 8 bscal slots, on wave 1
        const int s = blockIdx.x * 8 + (tid - 64);
        const double c0 = bscal[s * 4 + 0], c1 = bscal[s * 4 + 1];
        const double c2 = bscal[s * 4 + 2], c3 = bscal[s * 4 + 3];
        part += -0.8 * c0 / 33554432.0 - 0.2 * c1 / 33554432.0
                - c2 / 4194304.0 - c3 / 4194304.0;
    }
#pragma unroll
    for (int off = 32; off > 0; off >>= 1) part += __shfl_down(part, off);
    __shared__ double red2[4];
    if ((tid & 63) == 0) red2[tid >> 6] = part;
    __syncthreads();
    if (tid == 0) atomicAdd(out, (float)(red2[0] + red2[1] + red2[2] + red2[3]));
}

// Fallback finisher (atomic path): cols already reduced, 32 blocks suffice.
__global__ __launch_bounds__(256) void bicon_finish(
    const float* __restrict__ col_i,
    const float* __restrict__ col_j,
    const float* __restrict__ col_x,
    const double* __restrict__ bscal,
    float* __restrict__ out)
{
    const int tid = threadIdx.x;
    const int col = blockIdx.x * 256 + tid;      // exactly NCOL threads total

    double part;
    {
        const float fi = col_i[col], fj = col_j[col], fx = col_x[col];
        part = (1.0 - (2.0 * (double)fx + 0.001) /
                      ((double)fi + (double)fj + 0.001)) / 8192.0;
    }
    if (tid < 64) {   // 64 bscal slots per block: 32 blocks * 64 = 2048 = NBLK
        const int s = blockIdx.x * 64 + tid;
        const double c0 = bscal[s * 4 + 0], c1 = bscal[s * 4 + 1];
        const double c2 = bscal[s * 4 + 2], c3 = bscal[s * 4 + 3];
        part += -0.8 * c0 / 33554432.0 - 0.2 * c1 / 33554432.0
                - c2 / 4194304.0 - c3 / 4194304.0;
    }
#pragma unroll
    for (int off = 32; off > 0; off >>= 1) part += __shfl_down(part, off);
    __shared__ double red[4];
    if ((tid & 63) == 0) red[tid >> 6] = part;
    __syncthreads();
    if (tid == 0) atomicAdd(out, (float)(red[0] + red[1] + red[2] + red[3]));
}

extern "C" void kernel_launch(void* const* d_in, const int* in_sizes, int n_in,
                              void* d_out, int out_size, void* d_ws, size_t ws_size,
                              hipStream_t stream) {
    const float* c_map      = (const float*)d_in[0];
    const int*   target     = (const int*)d_in[1];
    const int*   con_target = (const int*)d_in[2];
    float* out = (float*)d_out;

    char* ws = (char*)d_ws;
    const size_t slab_need = (size_t)3 * SLABN * sizeof(float)
                           + (size_t)NBLK * 4 * sizeof(double);   // ~12.65 MB

    dim3 grid(GX, Bn);       // 128 x 16 = 2048 blocks
    dim3 block(256);

    hipMemsetAsync(d_out, 0, sizeof(float), stream);  // finisher atomics here

    if (ws_size >= slab_need) {
        float*  pI    = (float*)ws;                   // 2048 x 512 partials
        float*  pJ    = pI + SLABN;
        float*  pX    = pJ + SLABN;
        double* bscal = (double*)(ws + (size_t)3 * SLABN * sizeof(float));
        // no col memset needed: slabs are fully written
        bicon_main<true><<<grid, block, 0, stream>>>(c_map, target, con_target,
                                                     pI, pJ, pX, bscal);
        bicon_finish_slab<<<FBLK2, 256, 0, stream>>>(pI, pJ, pX, bscal, out);
    } else {
        float*  col_i = (float*)ws;                               // 8192 floats
        float*  col_j = col_i + NCOL;
        float*  col_x = col_j + NCOL;
        double* bscal = (double*)(ws + 3 * NCOL * sizeof(float)); // 2048*4 doubles
        hipMemsetAsync(d_ws, 0, 3 * NCOL * sizeof(float), stream);
        bicon_main<false><<<grid, block, 0, stream>>>(c_map, target, con_target,
                                                      col_i, col_j, col_x, bscal);
        bicon_finish<<<FBLK, 256, 0, stream>>>(col_i, col_j, col_x, bscal, out);
    }
}